// Round 1
// baseline (815.204 us; speedup 1.0000x reference)
//
#include <hip/hip_runtime.h>

#define BB 512
#define NN 50000
#define DD 64
#define HH 600
#define LL 200

#define K1 50016      // padded K for GEMM1 (1563*32)
#define KS1 1563      // K1/32
#define N1P 704       // padded out-cols of GEMM1 (600 W1a + 64 item_emb + pad), 11*64
#define KSPLIT 32
#define CHUNK 49      // ceil(1563/32)

#define K2 608        // padded K for GEMM2 (19*32)
#define N2P 50048     // padded N for GEMM2 (782*64)

typedef __attribute__((ext_vector_type(8))) short bf16x8;
typedef __attribute__((ext_vector_type(4))) float f32x4;

__device__ __forceinline__ unsigned short f2bf(float f) {
  union { float f; unsigned u; } v; v.f = f;
  unsigned r = v.u + 0x7fffu + ((v.u >> 16) & 1u);
  return (unsigned short)(r >> 16);
}

// ---------- inputs fp32 -> bf16 (K-padded) + per-row count + zero kl slot ----------
__global__ __launch_bounds__(256) void k_convA(const float* __restrict__ inp,
                                               unsigned short* __restrict__ A,
                                               float* __restrict__ cnt,
                                               float* __restrict__ outkl) {
  int b = blockIdx.x, tid = threadIdx.x;
  const float4* row4 = (const float4*)(inp + (size_t)b * NN);
  unsigned short* arow = A + (size_t)b * K1;
  float c = 0.f;
  for (int i = tid; i < K1 / 4; i += 256) {
    float4 f = make_float4(0.f, 0.f, 0.f, 0.f);
    if (i < NN / 4) f = row4[i];
    c += f.x + f.y + f.z + f.w;
    ushort4 u;
    u.x = f2bf(f.x); u.y = f2bf(f.y); u.z = f2bf(f.z); u.w = f2bf(f.w);
    ((ushort4*)arow)[i] = u;
  }
  __shared__ float sred[256];
  sred[tid] = c; __syncthreads();
  for (int s = 128; s > 0; s >>= 1) { if (tid < s) sred[tid] += sred[tid + s]; __syncthreads(); }
  if (tid == 0) { cnt[b] = sred[0]; if (b == 0) *outkl = 0.f; }
}

// ---------- B1 = [W1a ; item_emb]^T -> bf16 [N1P][K1] (k-contiguous) ----------
__global__ __launch_bounds__(256) void k_convB1(const float* __restrict__ W1,
                                                const float* __restrict__ item_emb,
                                                unsigned short* __restrict__ BT) {
  __shared__ unsigned short lds[64][65];
  int k0 = blockIdx.x * 64, j0 = blockIdx.y * 64;
  int tx = threadIdx.x & 63, ty = threadIdx.x >> 6;
  int j = j0 + tx;
#pragma unroll
  for (int r = 0; r < 16; ++r) {
    int k = k0 + ty + 4 * r;
    float v = 0.f;
    if (k < NN) {
      if (j < HH) v = W1[(size_t)k * HH + j];
      else if (j < HH + DD) v = item_emb[(size_t)k * DD + (j - HH)];
    }
    lds[tx][ty + 4 * r] = f2bf(v);
  }
  __syncthreads();
#pragma unroll
  for (int r = 0; r < 16; ++r) {
    int jj = j0 + ty + 4 * r;
    int kk = k0 + tx;
    if (kk < K1) BT[(size_t)jj * K1 + kk] = lds[ty + 4 * r][tx];
  }
}

// ---------- Wd2^T -> bf16 [N2P][K2] (k-contiguous) ----------
__global__ __launch_bounds__(256) void k_convB2(const float* __restrict__ Wd2,
                                                unsigned short* __restrict__ WT) {
  __shared__ unsigned short lds[64][65];
  int n0 = blockIdx.x * 64, k0 = blockIdx.y * 64;
  int tx = threadIdx.x & 63, ty = threadIdx.x >> 6;
  int n = n0 + tx;
#pragma unroll
  for (int r = 0; r < 16; ++r) {
    int k = k0 + ty + 4 * r;
    float v = 0.f;
    if (k < HH && n < NN) v = Wd2[(size_t)k * NN + n];
    lds[tx][ty + 4 * r] = f2bf(v);
  }
  __syncthreads();
#pragma unroll
  for (int r = 0; r < 16; ++r) {
    int nn = n0 + ty + 4 * r;
    int kk = k0 + tx;
    if (kk < K2) WT[(size_t)nn * K2 + kk] = lds[ty + 4 * r][tx];
  }
}

// ---------- GEMM1: [512 x K1] x [K1 x N1P] -> Ppart[s][512][N1P], split-K ----------
__global__ __launch_bounds__(256) void k_gemm1(const unsigned short* __restrict__ A,
                                               const unsigned short* __restrict__ BT,
                                               float* __restrict__ Ppart) {
  int wave = threadIdx.x >> 6, lane = threadIdx.x & 63;
  int s = blockIdx.z * 4 + wave;          // k-chunk 0..31
  int m0 = blockIdx.y * 64, n0 = blockIdx.x * 64;
  int lr = lane & 15, lk = (lane >> 4) * 8;

  const unsigned short* ap = A + (size_t)(m0 + lr) * K1 + lk;
  const unsigned short* bp = BT + (size_t)(n0 + lr) * K1 + lk;

  f32x4 acc[4][4] = {};
  int ks0 = s * CHUNK;
  int ks1 = ks0 + CHUNK; if (ks1 > KS1) ks1 = KS1;

  for (int ks = ks0; ks < ks1; ++ks) {
    int kb = ks * 32;
    bf16x8 a[4], b[4];
#pragma unroll
    for (int i = 0; i < 4; ++i) a[i] = *(const bf16x8*)(ap + (size_t)i * 16 * K1 + kb);
#pragma unroll
    for (int i = 0; i < 4; ++i) b[i] = *(const bf16x8*)(bp + (size_t)i * 16 * K1 + kb);
#pragma unroll
    for (int i = 0; i < 4; ++i)
#pragma unroll
      for (int j = 0; j < 4; ++j)
        acc[i][j] = __builtin_amdgcn_mfma_f32_16x16x32_bf16(a[i], b[j], acc[i][j], 0, 0, 0);
  }

  float* op = Ppart + (size_t)s * BB * N1P;
  int row0 = (lane >> 4) * 4, col = lane & 15;
#pragma unroll
  for (int i = 0; i < 4; ++i)
#pragma unroll
    for (int j = 0; j < 4; ++j)
#pragma unroll
      for (int r = 0; r < 4; ++r)
        op[(size_t)(m0 + i * 16 + row0 + r) * N1P + (n0 + j * 16 + col)] = acc[i][j][r];
}

// ---------- sum the 32 K-split partials ----------
__global__ __launch_bounds__(256) void k_reduceP(const float* __restrict__ Ppart,
                                                 float* __restrict__ P) {
  size_t e = (size_t)blockIdx.x * 256 + threadIdx.x;
  float s = 0.f;
#pragma unroll
  for (int c = 0; c < KSPLIT; ++c) s += Ppart[(size_t)c * BB * N1P + e];
  P[e] = s;
}

// ---------- fused middle: pooled/l2n -> h -> z -> kl -> t(bf16, padded) ----------
__global__ __launch_bounds__(256) void k_mid(const float* __restrict__ P,
                                             const float* __restrict__ cntb,
                                             const float* __restrict__ W1,
                                             const float* __restrict__ b1,
                                             const float* __restrict__ Wm,
                                             const float* __restrict__ bm,
                                             const float* __restrict__ Wv,
                                             const float* __restrict__ bv,
                                             const float* __restrict__ Wd1,
                                             const float* __restrict__ bd1,
                                             const float* __restrict__ eps,
                                             unsigned short* __restrict__ TB,
                                             float* __restrict__ outkl) {
  int b = blockIdx.x, tid = threadIdx.x;
  __shared__ float pn[DD];
  __shared__ float h[HH];
  __shared__ float z[LL];
  __shared__ float red[1];
  __shared__ float sred[256];

  float cnt = cntb[b];
  if (tid < 64) {
    float pooled = P[(size_t)b * N1P + HH + tid] / fmaxf(cnt, 1.f);
    float s2 = pooled * pooled;
    for (int o = 32; o > 0; o >>= 1) s2 += __shfl_xor(s2, o);
    float pnv = pooled * rsqrtf(fmaxf(s2, 1e-12f));
    pn[tid] = pnv;
    float p2 = pnv * pnv;
    for (int o = 32; o > 0; o >>= 1) p2 += __shfl_xor(p2, o);
    if (tid == 0) red[0] = rsqrtf(fmaxf(cnt + p2, 1e-12f));
  }
  __syncthreads();
  float inv = red[0];

  for (int j = tid; j < HH; j += 256) {
    float corr = 0.f;
#pragma unroll 8
    for (int d = 0; d < DD; ++d) corr += pn[d] * W1[(size_t)(NN + d) * HH + j];
    h[j] = tanhf((P[(size_t)b * N1P + j] + corr) * inv + b1[j]);
  }
  __syncthreads();

  float klp = 0.f;
  for (int l = tid; l < LL; l += 256) {
    float zm = bm[l], zv = bv[l];
    for (int j = 0; j < HH; ++j) {
      float hv = h[j];
      zm += hv * Wm[(size_t)j * LL + l];
      zv += hv * Wv[(size_t)j * LL + l];
    }
    z[l] = zm + expf(0.5f * zv) * eps[(size_t)b * LL + l];
    klp += zv - zm * zm - expf(zv) + 1.f;
  }
  sred[tid] = klp; __syncthreads();
  for (int s = 128; s > 0; s >>= 1) { if (tid < s) sred[tid] += sred[tid + s]; __syncthreads(); }
  if (tid == 0) atomicAdd(outkl, sred[0] * (-0.5f / (float)(BB * LL)));

  for (int j = tid; j < K2; j += 256) {
    unsigned short o = 0;
    if (j < HH) {
      float acc = bd1[j];
      for (int l = 0; l < LL; ++l) acc += z[l] * Wd1[(size_t)l * HH + j];
      o = f2bf(tanhf(acc));
    }
    TB[(size_t)b * K2 + j] = o;
  }
}

// ---------- GEMM2: [512 x K2] x [K2 x N2P] -> out + bias ----------
__global__ __launch_bounds__(256) void k_gemm2(const unsigned short* __restrict__ T,
                                               const unsigned short* __restrict__ WT,
                                               const float* __restrict__ bd2,
                                               float* __restrict__ out) {
  int wave = threadIdx.x >> 6, lane = threadIdx.x & 63;
  int wm = wave >> 1, wn = wave & 1;
  int m0 = blockIdx.y * 128 + wm * 64;
  int n0 = blockIdx.x * 128 + wn * 64;
  int lr = lane & 15, lk = (lane >> 4) * 8;

  const unsigned short* ap = T + (size_t)(m0 + lr) * K2 + lk;
  const unsigned short* bp = WT + (size_t)(n0 + lr) * K2 + lk;

  f32x4 acc[4][4] = {};
#pragma unroll
  for (int ks = 0; ks < K2 / 32; ++ks) {
    int kb = ks * 32;
    bf16x8 a[4], b[4];
#pragma unroll
    for (int i = 0; i < 4; ++i) a[i] = *(const bf16x8*)(ap + (size_t)i * 16 * K2 + kb);
#pragma unroll
    for (int i = 0; i < 4; ++i) b[i] = *(const bf16x8*)(bp + (size_t)i * 16 * K2 + kb);
#pragma unroll
    for (int i = 0; i < 4; ++i)
#pragma unroll
      for (int j = 0; j < 4; ++j)
        acc[i][j] = __builtin_amdgcn_mfma_f32_16x16x32_bf16(a[i], b[j], acc[i][j], 0, 0, 0);
  }

  int row0 = (lane >> 4) * 4, col = lane & 15;
#pragma unroll
  for (int i = 0; i < 4; ++i)
#pragma unroll
    for (int j = 0; j < 4; ++j) {
      int n = n0 + j * 16 + col;
      if (n < NN) {
        float bias = bd2[n];
#pragma unroll
        for (int r = 0; r < 4; ++r) {
          int m = m0 + i * 16 + row0 + r;
          out[(size_t)m * NN + n] = acc[i][j][r] + bias;
        }
      }
    }
}

extern "C" void kernel_launch(void* const* d_in, const int* in_sizes, int n_in,
                              void* d_out, int out_size, void* d_ws, size_t ws_size,
                              hipStream_t stream) {
  (void)in_sizes; (void)n_in; (void)out_size; (void)ws_size;
  const float* inputs   = (const float*)d_in[0];
  const float* item_emb = (const float*)d_in[1];
  const float* W1  = (const float*)d_in[2];
  const float* b1  = (const float*)d_in[3];
  const float* Wm  = (const float*)d_in[4];
  const float* bm  = (const float*)d_in[5];
  const float* Wv  = (const float*)d_in[6];
  const float* bv  = (const float*)d_in[7];
  const float* Wd1 = (const float*)d_in[8];
  const float* bd1 = (const float*)d_in[9];
  const float* Wd2 = (const float*)d_in[10];
  const float* bd2 = (const float*)d_in[11];
  const float* eps = (const float*)d_in[12];
  float* out = (float*)d_out;

  char* ws = (char*)d_ws;
  unsigned short* A   = (unsigned short*)(ws + 0ull);           // 512*50016*2   = 51,216,384
  unsigned short* BT1 = (unsigned short*)(ws + 51216384ull);    // 704*50016*2   = 70,422,528
  unsigned short* W2T = (unsigned short*)(ws + 121638912ull);   // 50048*608*2   = 60,858,368
  float* Ppart        = (float*)(ws + 182497280ull);            // 32*512*704*4  = 46,137,344
  float* P            = (float*)(ws + 228634624ull);            // 512*704*4     =  1,441,792
  unsigned short* TB  = (unsigned short*)(ws + 230076416ull);   // 512*608*2     =    622,592
  float* cnt          = (float*)(ws + 230699008ull);            // 512*4

  float* outkl = out + (size_t)BB * NN;

  k_convA <<<dim3(BB),      dim3(256), 0, stream>>>(inputs, A, cnt, outkl);
  k_convB1<<<dim3(782, 11), dim3(256), 0, stream>>>(W1, item_emb, BT1);
  k_convB2<<<dim3(782, 10), dim3(256), 0, stream>>>(Wd2, W2T);
  k_gemm1 <<<dim3(11, 8, 8), dim3(256), 0, stream>>>(A, BT1, Ppart);
  k_reduceP<<<dim3((BB * N1P) / 256), dim3(256), 0, stream>>>(Ppart, P);
  k_mid   <<<dim3(BB),      dim3(256), 0, stream>>>(P, cnt, W1, b1, Wm, bm, Wv, bv, Wd1, bd1, eps, TB, outkl);
  k_gemm2 <<<dim3(391, 4),  dim3(256), 0, stream>>>(TB, W2T, bd2, out);
}

// Round 3
// 799.309 us; speedup vs baseline: 1.0199x; 1.0199x over previous
//
#include <hip/hip_runtime.h>

#define BB 512
#define NN 50000
#define DD 64
#define HH 600
#define LL 200

#define K1 50176      // padded K for GEMM1: 32 chunks * 1568, 784*64
#define S1 1568       // mask words per row = K1/32
#define N1P 704       // padded out-cols of GEMM1 (600 W1 + 64 item_emb + 40 pad)
#define KCH 49        // k-steps (of 32) per k-chunk; 32 chunks * 49 = 1568

#define K2 608        // padded K for GEMM2 (19*32)
#define N2P 50048     // padded N for GEMM2 (782*64)

typedef __attribute__((ext_vector_type(8))) short bf16x8;
typedef __attribute__((ext_vector_type(4))) float f32x4;

__device__ __forceinline__ unsigned short f2bf(float f) {
  union { float f; unsigned u; } v; v.f = f;
  unsigned r = v.u + 0x7fffu + ((v.u >> 16) & 1u);
  return (unsigned short)(r >> 16);
}

// ---------- prep: inputs -> bitmask + count; zero P and kl ----------
__global__ __launch_bounds__(256) void k_prep(const float* __restrict__ inp,
                                              unsigned* __restrict__ mask,
                                              float* __restrict__ cnt,
                                              float* __restrict__ P,
                                              float* __restrict__ outkl) {
  int b = blockIdx.x, tid = threadIdx.x;
  const float4* row4 = (const float4*)(inp + (size_t)b * NN);
  unsigned* mrow = mask + (size_t)b * S1;
  int c = 0;
  for (int w = tid; w < S1; w += 256) {
    unsigned m = 0;
    int kb = w * 32;
    if (kb + 32 <= NN) {
#pragma unroll
      for (int q = 0; q < 8; ++q) {
        float4 f = row4[w * 8 + q];
        m |= (f.x > 0.5f ? 1u : 0u) << (4 * q);
        m |= (f.y > 0.5f ? 1u : 0u) << (4 * q + 1);
        m |= (f.z > 0.5f ? 1u : 0u) << (4 * q + 2);
        m |= (f.w > 0.5f ? 1u : 0u) << (4 * q + 3);
      }
    } else {
      for (int k = kb; k < NN && k < kb + 32; ++k)
        m |= (inp[(size_t)b * NN + k] > 0.5f ? 1u : 0u) << (k - kb);
    }
    mrow[w] = m;
    c += __popc(m);
  }
  __shared__ int sred[256];
  sred[tid] = c; __syncthreads();
  for (int s = 128; s > 0; s >>= 1) { if (tid < s) sred[tid] += sred[tid + s]; __syncthreads(); }
  if (tid == 0) cnt[b] = (float)sred[0];
  for (int j = tid; j < N1P; j += 256) P[(size_t)b * N1P + j] = 0.f;
  if (b == 0 && tid == 0) *outkl = 0.f;
}

// ---------- B1 = [W1a ; item_emb]^T -> bf16 [N1P][K1] (k-contiguous) ----------
__global__ __launch_bounds__(256) void k_convB1(const float* __restrict__ W1,
                                                const float* __restrict__ item_emb,
                                                unsigned short* __restrict__ BT) {
  __shared__ unsigned short lds[64][65];
  int k0 = blockIdx.x * 64, j0 = blockIdx.y * 64;
  int tx = threadIdx.x & 63, ty = threadIdx.x >> 6;
  int j = j0 + tx;
#pragma unroll
  for (int r = 0; r < 16; ++r) {
    int k = k0 + ty + 4 * r;
    float v = 0.f;
    if (k < NN) {
      if (j < HH) v = W1[(size_t)k * HH + j];
      else if (j < HH + DD) v = item_emb[(size_t)k * DD + (j - HH)];
    }
    lds[tx][ty + 4 * r] = f2bf(v);
  }
  __syncthreads();
#pragma unroll
  for (int r = 0; r < 16; ++r) {
    int jj = j0 + ty + 4 * r;
    int kk = k0 + tx;
    BT[(size_t)jj * K1 + kk] = lds[ty + 4 * r][tx];
  }
}

// ---------- Wd2^T -> bf16 [N2P][K2] (k-contiguous) ----------
__global__ __launch_bounds__(256) void k_convB2(const float* __restrict__ Wd2,
                                                unsigned short* __restrict__ WT) {
  __shared__ unsigned short lds[64][65];
  int n0 = blockIdx.x * 64, k0 = blockIdx.y * 64;
  int tx = threadIdx.x & 63, ty = threadIdx.x >> 6;
  int n = n0 + tx;
#pragma unroll
  for (int r = 0; r < 16; ++r) {
    int k = k0 + ty + 4 * r;
    float v = 0.f;
    if (k < HH && n < NN) v = Wd2[(size_t)k * NN + n];
    lds[tx][ty + 4 * r] = f2bf(v);
  }
  __syncthreads();
#pragma unroll
  for (int r = 0; r < 16; ++r) {
    int nn = n0 + ty + 4 * r;
    int kk = k0 + tx;
    if (kk < K2) WT[(size_t)nn * K2 + kk] = lds[ty + 4 * r][tx];
  }
}

// ---------- GEMM1: bitmask A [512 x K1 bits] x BT1 -> atomicAdd P[512][N1P] ----------
// grid (11 n-blocks, 32 k-chunks), 512 threads = 8 waves, wave w -> rows [64w,64w+64)
__global__ __launch_bounds__(512) void k_gemm1(const unsigned* __restrict__ mask,
                                               const unsigned short* __restrict__ BT,
                                               float* __restrict__ P) {
  int wave = threadIdx.x >> 6, lane = threadIdx.x & 63;
  int n0 = blockIdx.x * 64;
  int m0 = wave * 64;
  int lr = lane & 15, kg = lane >> 4;

  const unsigned short* bp = BT + (size_t)(n0 + lr) * K1 + kg * 8;

  f32x4 acc[4][4] = {};
  int s0 = blockIdx.y * KCH, s1 = s0 + KCH;

  union AU { unsigned u[4]; bf16x8 v; };

  for (int s = s0; s < s1; ++s) {
    int kb = s * 32;
    bf16x8 b[4];
#pragma unroll
    for (int j = 0; j < 4; ++j)
      b[j] = *(const bf16x8*)(bp + (size_t)j * 16 * K1 + kb);

    bf16x8 a[4];
#pragma unroll
    for (int i = 0; i < 4; ++i) {
      unsigned mw = mask[(size_t)(m0 + i * 16 + lr) * S1 + s];
      unsigned byte = (mw >> (kg * 8)) & 0xFFu;
      AU au;
#pragma unroll
      for (int p = 0; p < 4; ++p) {
        unsigned t = (byte >> (2 * p)) & 3u;
        t = (t | (t << 15)) & 0x10001u;
        au.u[p] = t * 0x3F80u;   // bf16 1.0 per set bit
      }
      a[i] = au.v;
    }

#pragma unroll
    for (int i = 0; i < 4; ++i)
#pragma unroll
      for (int j = 0; j < 4; ++j)
        acc[i][j] = __builtin_amdgcn_mfma_f32_16x16x32_bf16(a[i], b[j], acc[i][j], 0, 0, 0);
  }

  int row0 = (lane >> 4) * 4, col = lane & 15;
#pragma unroll
  for (int i = 0; i < 4; ++i)
#pragma unroll
    for (int j = 0; j < 4; ++j)
#pragma unroll
      for (int r = 0; r < 4; ++r)
        atomicAdd(&P[(size_t)(m0 + i * 16 + row0 + r) * N1P + (n0 + j * 16 + col)], acc[i][j][r]);
}

// ---------- fused middle: pooled/l2n -> h -> z -> kl -> t(bf16, padded) ----------
__global__ __launch_bounds__(256) void k_mid(const float* __restrict__ P,
                                             const float* __restrict__ cntb,
                                             const float* __restrict__ W1,
                                             const float* __restrict__ b1,
                                             const float* __restrict__ Wm,
                                             const float* __restrict__ bm,
                                             const float* __restrict__ Wv,
                                             const float* __restrict__ bv,
                                             const float* __restrict__ Wd1,
                                             const float* __restrict__ bd1,
                                             const float* __restrict__ eps,
                                             unsigned short* __restrict__ TB,
                                             float* __restrict__ outkl) {
  int b = blockIdx.x, tid = threadIdx.x;
  __shared__ float pn[DD];
  __shared__ float h[HH];
  __shared__ float z[LL];
  __shared__ float red[1];
  __shared__ float sred[256];

  float cnt = cntb[b];
  if (tid < 64) {
    float pooled = P[(size_t)b * N1P + HH + tid] / fmaxf(cnt, 1.f);
    float s2 = pooled * pooled;
    for (int o = 32; o > 0; o >>= 1) s2 += __shfl_xor(s2, o);
    float pnv = pooled * rsqrtf(fmaxf(s2, 1e-12f));
    pn[tid] = pnv;
    float p2 = pnv * pnv;
    for (int o = 32; o > 0; o >>= 1) p2 += __shfl_xor(p2, o);
    if (tid == 0) red[0] = rsqrtf(fmaxf(cnt + p2, 1e-12f));
  }
  __syncthreads();
  float inv = red[0];

  for (int j = tid; j < HH; j += 256) {
    float corr = 0.f;
#pragma unroll 8
    for (int d = 0; d < DD; ++d) corr += pn[d] * W1[(size_t)(NN + d) * HH + j];
    h[j] = tanhf((P[(size_t)b * N1P + j] + corr) * inv + b1[j]);
  }
  __syncthreads();

  float klp = 0.f;
  for (int l = tid; l < LL; l += 256) {
    float zm = bm[l], zv = bv[l];
    for (int j = 0; j < HH; ++j) {
      float hv = h[j];
      zm += hv * Wm[(size_t)j * LL + l];
      zv += hv * Wv[(size_t)j * LL + l];
    }
    z[l] = zm + expf(0.5f * zv) * eps[(size_t)b * LL + l];
    klp += zv - zm * zm - expf(zv) + 1.f;
  }
  sred[tid] = klp; __syncthreads();
  for (int s = 128; s > 0; s >>= 1) { if (tid < s) sred[tid] += sred[tid + s]; __syncthreads(); }
  if (tid == 0) atomicAdd(outkl, sred[0] * (-0.5f / (float)(BB * LL)));

  for (int j = tid; j < K2; j += 256) {
    unsigned short o = 0;
    if (j < HH) {
      float acc = bd1[j];
      for (int l = 0; l < LL; ++l) acc += z[l] * Wd1[(size_t)l * HH + j];
      o = f2bf(tanhf(acc));
    }
    TB[(size_t)b * K2 + j] = o;
  }
}

// ---------- GEMM2: [512 x K2] x W2T -> out + bias; full-M tile, B read once ----------
// grid (782 n-blocks), 512 threads = 8 waves, wave w -> rows [64w,64w+64)
__global__ __launch_bounds__(512) void k_gemm2(const unsigned short* __restrict__ T,
                                               const unsigned short* __restrict__ WT,
                                               const float* __restrict__ bd2,
                                               float* __restrict__ out) {
  int wave = threadIdx.x >> 6, lane = threadIdx.x & 63;
  int n0 = blockIdx.x * 64;
  int m0 = wave * 64;
  int lr = lane & 15, lk = (lane >> 4) * 8;

  const unsigned short* ap = T + (size_t)(m0 + lr) * K2 + lk;
  const unsigned short* bp = WT + (size_t)(n0 + lr) * K2 + lk;

  f32x4 acc[4][4] = {};
#pragma unroll
  for (int ks = 0; ks < K2 / 32; ++ks) {
    int kb = ks * 32;
    bf16x8 a[4], b[4];
#pragma unroll
    for (int i = 0; i < 4; ++i) a[i] = *(const bf16x8*)(ap + (size_t)i * 16 * K2 + kb);
#pragma unroll
    for (int i = 0; i < 4; ++i) b[i] = *(const bf16x8*)(bp + (size_t)i * 16 * K2 + kb);
#pragma unroll
    for (int i = 0; i < 4; ++i)
#pragma unroll
      for (int j = 0; j < 4; ++j)
        acc[i][j] = __builtin_amdgcn_mfma_f32_16x16x32_bf16(a[i], b[j], acc[i][j], 0, 0, 0);
  }

  int row0 = (lane >> 4) * 4, col = lane & 15;
#pragma unroll
  for (int i = 0; i < 4; ++i)
#pragma unroll
    for (int j = 0; j < 4; ++j) {
      int n = n0 + j * 16 + col;
      if (n < NN) {
        float bias = bd2[n];
#pragma unroll
        for (int r = 0; r < 4; ++r) {
          int m = m0 + i * 16 + row0 + r;
          out[(size_t)m * NN + n] = acc[i][j][r] + bias;
        }
      }
    }
}

extern "C" void kernel_launch(void* const* d_in, const int* in_sizes, int n_in,
                              void* d_out, int out_size, void* d_ws, size_t ws_size,
                              hipStream_t stream) {
  (void)in_sizes; (void)n_in; (void)out_size; (void)ws_size;
  const float* inputs   = (const float*)d_in[0];
  const float* item_emb = (const float*)d_in[1];
  const float* W1  = (const float*)d_in[2];
  const float* b1  = (const float*)d_in[3];
  const float* Wm  = (const float*)d_in[4];
  const float* bm  = (const float*)d_in[5];
  const float* Wv  = (const float*)d_in[6];
  const float* bv  = (const float*)d_in[7];
  const float* Wd1 = (const float*)d_in[8];
  const float* bd1 = (const float*)d_in[9];
  const float* Wd2 = (const float*)d_in[10];
  const float* bd2 = (const float*)d_in[11];
  const float* eps = (const float*)d_in[12];
  float* out = (float*)d_out;

  char* ws = (char*)d_ws;
  unsigned* mask      = (unsigned*)(ws + 0ull);                 // 512*1568*4   =  3,211,264
  unsigned short* BT1 = (unsigned short*)(ws + 3211264ull);     // 704*50176*2  = 70,647,808
  unsigned short* W2T = (unsigned short*)(ws + 73859072ull);    // 50048*608*2  = 60,858,368
  float* P            = (float*)(ws + 134717440ull);            // 512*704*4    =  1,441,792
  unsigned short* TB  = (unsigned short*)(ws + 136159232ull);   // 512*608*2    =    622,592
  float* cnt          = (float*)(ws + 136781824ull);            // 512*4

  float* outkl = out + (size_t)BB * NN;

  k_prep  <<<dim3(BB),       dim3(256), 0, stream>>>(inputs, mask, cnt, P, outkl);
  k_convB1<<<dim3(784, 11),  dim3(256), 0, stream>>>(W1, item_emb, BT1);
  k_convB2<<<dim3(782, 10),  dim3(256), 0, stream>>>(Wd2, W2T);
  k_gemm1 <<<dim3(11, 32),   dim3(512), 0, stream>>>(mask, BT1, P);
  k_mid   <<<dim3(BB),       dim3(256), 0, stream>>>(P, cnt, W1, b1, Wm, bm, Wv, bv, Wd1, bd1, eps, TB, outkl);
  k_gemm2 <<<dim3(782),      dim3(512), 0, stream>>>(TB, W2T, bd2, out);
}

// Round 5
// 704.362 us; speedup vs baseline: 1.1574x; 1.1348x over previous
//
#include <hip/hip_runtime.h>

#define BB 512
#define NN 50000
#define DD 64
#define HH 600
#define LL 200

#define K1 50176      // padded K for GEMM1 (28 chunks * 1792)
#define S1 1568       // mask words per row = K1/32
#define N1P 704       // padded out-cols of GEMM1 (600 W1 + 64 item_emb + 40 pad)
#define NCH 28        // k-chunks (split-K)
#define CKE 1792      // k-elements per chunk
#define CW 56         // mask words per chunk
#define NST 14        // stages per chunk (BK=128)

#define K2P 640       // padded K for GEMM2 (5 stages * 128)
#define N2P 50048     // padded N for GEMM2 (782*64)

typedef __attribute__((ext_vector_type(8))) short bf16x8;
typedef __attribute__((ext_vector_type(4))) float f32x4;

__device__ __forceinline__ unsigned short f2bf(float f) {
  union { float f; unsigned u; } v; v.f = f;
  unsigned r = v.u + 0x7fffu + ((v.u >> 16) & 1u);
  return (unsigned short)(r >> 16);
}

__device__ __forceinline__ void g2l16(const void* g, void* l) {
  __builtin_amdgcn_global_load_lds((const __attribute__((address_space(1))) unsigned int*)g,
                                   (__attribute__((address_space(3))) unsigned int*)l, 16, 0, 0);
}

// ---------- prep: inputs -> TRANSPOSED bitmask maskT[word][row] + count; zero P, kl ----------
__global__ __launch_bounds__(256) void k_prep(const float* __restrict__ inp,
                                              unsigned* __restrict__ maskT,
                                              float* __restrict__ cnt,
                                              float* __restrict__ P,
                                              float* __restrict__ outkl) {
  int b = blockIdx.x, tid = threadIdx.x;
  const float4* row4 = (const float4*)(inp + (size_t)b * NN);
  int c = 0;
  for (int w = tid; w < S1; w += 256) {
    unsigned m = 0;
    int kb = w * 32;
    if (kb + 32 <= NN) {
#pragma unroll
      for (int q = 0; q < 8; ++q) {
        float4 f = row4[w * 8 + q];
        m |= (f.x > 0.5f ? 1u : 0u) << (4 * q);
        m |= (f.y > 0.5f ? 1u : 0u) << (4 * q + 1);
        m |= (f.z > 0.5f ? 1u : 0u) << (4 * q + 2);
        m |= (f.w > 0.5f ? 1u : 0u) << (4 * q + 3);
      }
    } else {
      for (int k = kb; k < NN && k < kb + 32; ++k)
        m |= (inp[(size_t)b * NN + k] > 0.5f ? 1u : 0u) << (k - kb);
    }
    maskT[(size_t)w * BB + b] = m;
    c += __popc(m);
  }
  __shared__ int sred[256];
  sred[tid] = c; __syncthreads();
  for (int s = 128; s > 0; s >>= 1) { if (tid < s) sred[tid] += sred[tid + s]; __syncthreads(); }
  if (tid == 0) cnt[b] = (float)sred[0];
  for (int j = tid; j < N1P; j += 256) P[(size_t)b * N1P + j] = 0.f;
  if (b == 0 && tid == 0) *outkl = 0.f;
}

// ---------- B1 = [W1a ; item_emb]^T -> bf16 [N1P][K1] (k-contiguous) ----------
__global__ __launch_bounds__(256) void k_convB1(const float* __restrict__ W1,
                                                const float* __restrict__ item_emb,
                                                unsigned short* __restrict__ BT) {
  __shared__ unsigned short lds[64][65];
  int k0 = blockIdx.x * 64, j0 = blockIdx.y * 64;
  int tx = threadIdx.x & 63, ty = threadIdx.x >> 6;
  int j = j0 + tx;
#pragma unroll
  for (int r = 0; r < 16; ++r) {
    int k = k0 + ty + 4 * r;
    float v = 0.f;
    if (k < NN) {
      if (j < HH) v = W1[(size_t)k * HH + j];
      else if (j < HH + DD) v = item_emb[(size_t)k * DD + (j - HH)];
    }
    lds[tx][ty + 4 * r] = f2bf(v);
  }
  __syncthreads();
#pragma unroll
  for (int r = 0; r < 16; ++r) {
    int jj = j0 + ty + 4 * r;
    int kk = k0 + tx;
    BT[(size_t)jj * K1 + kk] = lds[ty + 4 * r][tx];
  }
}

// ---------- Wd2^T -> bf16 [N2P][K2P] (k-contiguous) ----------
__global__ __launch_bounds__(256) void k_convB2(const float* __restrict__ Wd2,
                                                unsigned short* __restrict__ WT) {
  __shared__ unsigned short lds[64][65];
  int n0 = blockIdx.x * 64, k0 = blockIdx.y * 64;
  int tx = threadIdx.x & 63, ty = threadIdx.x >> 6;
  int n = n0 + tx;
#pragma unroll
  for (int r = 0; r < 16; ++r) {
    int k = k0 + ty + 4 * r;
    float v = 0.f;
    if (k < HH && n < NN) v = Wd2[(size_t)k * NN + n];
    lds[tx][ty + 4 * r] = f2bf(v);
  }
  __syncthreads();
#pragma unroll
  for (int r = 0; r < 16; ++r) {
    int nn = n0 + ty + 4 * r;
    int kk = k0 + tx;
    WT[(size_t)nn * K2P + kk] = lds[ty + 4 * r][tx];
  }
}

// ---------- GEMM1: bitmask A x BT1 -> atomicAdd P; LDS-staged B + mask, 2-phase pipeline ----------
// grid (11 n-blocks, 28 k-chunks), 512 threads = 8 waves, wave w -> rows [64w, 64w+64)
__global__ __launch_bounds__(512) void k_gemm1(const unsigned* __restrict__ maskT,
                                               const unsigned short* __restrict__ BT,
                                               float* __restrict__ P) {
  __shared__ unsigned short sB[2 * 8192];  // 2 x 16KB: [64 rows][128 k] bf16, XOR-swizzled
  __shared__ unsigned sM[2 * 2048];        // 2 x 8KB:  [4 words][512 rows]
  int tid = threadIdx.x;
  int wave = tid >> 6, lane = tid & 63;
  int lr = lane & 15, kg = lane >> 4;
  int n0 = blockIdx.x * 64;
  int m0 = wave * 64;
  int cK = blockIdx.y * CKE;
  int cWo = blockIdx.y * CW;

  auto stage = [&](int p, int st) {
    int kb = cK + st * 128;
#pragma unroll
    for (int i = 0; i < 2; ++i) {
      int row = wave * 8 + i * 4 + kg;
      int cbs = (lr * 16) ^ ((row & 7) << 4);      // inverse-swizzled source col (bytes)
      const unsigned short* src = BT + (size_t)(n0 + row) * K1 + kb + (cbs >> 1);
      unsigned short* dst = sB + p * 8192 + wave * 1024 + i * 512;
      g2l16(src, dst);
    }
    int w0 = cWo + st * 4;
    const unsigned* msrc = maskT + (size_t)w0 * BB + wave * 256 + lane * 4;
    unsigned* mdst = sM + p * 2048 + wave * 256;
    g2l16(msrc, mdst);
  };

  stage(0, 0);
  f32x4 acc[4][4] = {};

  for (int st = 0; st < NST; ++st) {
    int cur = st & 1;
    if (st + 1 < NST) {
      stage(cur ^ 1, st + 1);
      asm volatile("s_waitcnt vmcnt(3)" ::: "memory");
    } else {
      asm volatile("s_waitcnt vmcnt(0)" ::: "memory");
    }
    __builtin_amdgcn_s_barrier();

    const unsigned short* Bb = sB + cur * 8192;
    const unsigned* Mb = sM + cur * 2048;
#pragma unroll
    for (int ks = 0; ks < 4; ++ks) {
      bf16x8 b[4];
#pragma unroll
      for (int j = 0; j < 4; ++j) {
        int row = j * 16 + lr;
        int cb = (ks * 64 + kg * 16) ^ ((row & 7) << 4);
        b[j] = *(const bf16x8*)(Bb + row * 128 + (cb >> 1));
      }
#pragma unroll
      for (int i = 0; i < 4; ++i) {
        unsigned mw = Mb[ks * 512 + m0 + i * 16 + lr];
        unsigned byt = (mw >> (kg * 8)) & 0xFFu;
        union { unsigned u[4]; bf16x8 v; } au;
#pragma unroll
        for (int p2 = 0; p2 < 4; ++p2) {
          unsigned t = (byt >> (2 * p2)) & 3u;
          t = (t | (t << 15)) & 0x10001u;
          au.u[p2] = t * 0x3F80u;   // bf16 1.0 per set bit
        }
#pragma unroll
        for (int j = 0; j < 4; ++j)
          acc[i][j] = __builtin_amdgcn_mfma_f32_16x16x32_bf16(au.v, b[j], acc[i][j], 0, 0, 0);
      }
    }
    __builtin_amdgcn_s_barrier();
  }

  int row0 = (lane >> 4) * 4, col = lane & 15;
#pragma unroll
  for (int i = 0; i < 4; ++i)
#pragma unroll
    for (int j = 0; j < 4; ++j)
#pragma unroll
      for (int r = 0; r < 4; ++r)
        atomicAdd(&P[(size_t)(m0 + i * 16 + row0 + r) * N1P + (n0 + j * 16 + col)], acc[i][j][r]);
}

// ---------- fused middle: pooled/l2n -> h -> z -> kl -> t(bf16, padded to K2P) ----------
__global__ __launch_bounds__(256) void k_mid(const float* __restrict__ P,
                                             const float* __restrict__ cntb,
                                             const float* __restrict__ W1,
                                             const float* __restrict__ b1,
                                             const float* __restrict__ Wm,
                                             const float* __restrict__ bm,
                                             const float* __restrict__ Wv,
                                             const float* __restrict__ bv,
                                             const float* __restrict__ Wd1,
                                             const float* __restrict__ bd1,
                                             const float* __restrict__ eps,
                                             unsigned short* __restrict__ TB,
                                             float* __restrict__ outkl) {
  int b = blockIdx.x, tid = threadIdx.x;
  __shared__ float pn[DD];
  __shared__ float h[HH];
  __shared__ float z[LL];
  __shared__ float red[1];
  __shared__ float sred[256];

  float cnt = cntb[b];
  if (tid < 64) {
    float pooled = P[(size_t)b * N1P + HH + tid] / fmaxf(cnt, 1.f);
    float s2 = pooled * pooled;
    for (int o = 32; o > 0; o >>= 1) s2 += __shfl_xor(s2, o);
    float pnv = pooled * rsqrtf(fmaxf(s2, 1e-12f));
    pn[tid] = pnv;
    float p2 = pnv * pnv;
    for (int o = 32; o > 0; o >>= 1) p2 += __shfl_xor(p2, o);
    if (tid == 0) red[0] = rsqrtf(fmaxf(cnt + p2, 1e-12f));
  }
  __syncthreads();
  float inv = red[0];

  for (int j = tid; j < HH; j += 256) {
    float corr = 0.f;
#pragma unroll 8
    for (int d = 0; d < DD; ++d) corr += pn[d] * W1[(size_t)(NN + d) * HH + j];
    h[j] = tanhf((P[(size_t)b * N1P + j] + corr) * inv + b1[j]);
  }
  __syncthreads();

  float klp = 0.f;
  for (int l = tid; l < LL; l += 256) {
    float zm = bm[l], zv = bv[l];
    for (int j = 0; j < HH; ++j) {
      float hv = h[j];
      zm += hv * Wm[(size_t)j * LL + l];
      zv += hv * Wv[(size_t)j * LL + l];
    }
    z[l] = zm + expf(0.5f * zv) * eps[(size_t)b * LL + l];
    klp += zv - zm * zm - expf(zv) + 1.f;
  }
  sred[tid] = klp; __syncthreads();
  for (int s = 128; s > 0; s >>= 1) { if (tid < s) sred[tid] += sred[tid + s]; __syncthreads(); }
  if (tid == 0) atomicAdd(outkl, sred[0] * (-0.5f / (float)(BB * LL)));

  for (int j = tid; j < K2P; j += 256) {
    unsigned short o = 0;
    if (j < HH) {
      float acc = bd1[j];
      for (int l = 0; l < LL; ++l) acc += z[l] * Wd1[(size_t)l * HH + j];
      o = f2bf(tanhf(acc));
    }
    TB[(size_t)b * K2P + j] = o;
  }
}

// ---------- GEMM2: [512 x K2P] x W2T -> out + bias; LDS-staged B, 2-phase pipeline ----------
// grid (782 n-blocks), 512 threads = 8 waves, wave w -> rows [64w, 64w+64)
__global__ __launch_bounds__(512) void k_gemm2(const unsigned short* __restrict__ T,
                                               const unsigned short* __restrict__ WT,
                                               const float* __restrict__ bd2,
                                               float* __restrict__ out) {
  __shared__ unsigned short sB[2 * 8192];  // 2 x 16KB, XOR-swizzled
  int tid = threadIdx.x;
  int wave = tid >> 6, lane = tid & 63;
  int lr = lane & 15, kg = lane >> 4;
  int n0 = blockIdx.x * 64;
  int m0 = wave * 64;

  auto stage = [&](int p, int st) {
    int kb = st * 128;
#pragma unroll
    for (int i = 0; i < 2; ++i) {
      int row = wave * 8 + i * 4 + kg;
      int cbs = (lr * 16) ^ ((row & 7) << 4);
      const unsigned short* src = WT + (size_t)(n0 + row) * K2P + kb + (cbs >> 1);
      unsigned short* dst = sB + p * 8192 + wave * 1024 + i * 512;
      g2l16(src, dst);
    }
  };

  stage(0, 0);
  f32x4 acc[4][4] = {};

  for (int st = 0; st < 5; ++st) {
    int cur = st & 1;
    if (st + 1 < 5) {
      stage(cur ^ 1, st + 1);
      asm volatile("s_waitcnt vmcnt(2)" ::: "memory");
    } else {
      asm volatile("s_waitcnt vmcnt(0)" ::: "memory");
    }
    __builtin_amdgcn_s_barrier();

    const unsigned short* Bb = sB + cur * 8192;
#pragma unroll
    for (int ks = 0; ks < 4; ++ks) {
      bf16x8 a[4], b[4];
#pragma unroll
      for (int i = 0; i < 4; ++i)
        a[i] = *(const bf16x8*)(T + (size_t)(m0 + i * 16 + lr) * K2P + st * 128 + ks * 32 + kg * 8);
#pragma unroll
      for (int j = 0; j < 4; ++j) {
        int row = j * 16 + lr;
        int cb = (ks * 64 + kg * 16) ^ ((row & 7) << 4);
        b[j] = *(const bf16x8*)(Bb + row * 128 + (cb >> 1));
      }
#pragma unroll
      for (int i = 0; i < 4; ++i)
#pragma unroll
        for (int j = 0; j < 4; ++j)
          acc[i][j] = __builtin_amdgcn_mfma_f32_16x16x32_bf16(a[i], b[j], acc[i][j], 0, 0, 0);
    }
    __builtin_amdgcn_s_barrier();
  }

  int row0 = (lane >> 4) * 4, col = lane & 15;
#pragma unroll
  for (int i = 0; i < 4; ++i)
#pragma unroll
    for (int j = 0; j < 4; ++j) {
      int n = n0 + j * 16 + col;
      if (n < NN) {
        float bias = bd2[n];
#pragma unroll
        for (int r = 0; r < 4; ++r) {
          int m = m0 + i * 16 + row0 + r;
          out[(size_t)m * NN + n] = acc[i][j][r] + bias;
        }
      }
    }
}

extern "C" void kernel_launch(void* const* d_in, const int* in_sizes, int n_in,
                              void* d_out, int out_size, void* d_ws, size_t ws_size,
                              hipStream_t stream) {
  (void)in_sizes; (void)n_in; (void)out_size; (void)ws_size;
  const float* inputs   = (const float*)d_in[0];
  const float* item_emb = (const float*)d_in[1];
  const float* W1  = (const float*)d_in[2];
  const float* b1  = (const float*)d_in[3];
  const float* Wm  = (const float*)d_in[4];
  const float* bm  = (const float*)d_in[5];
  const float* Wv  = (const float*)d_in[6];
  const float* bv  = (const float*)d_in[7];
  const float* Wd1 = (const float*)d_in[8];
  const float* bd1 = (const float*)d_in[9];
  const float* Wd2 = (const float*)d_in[10];
  const float* bd2 = (const float*)d_in[11];
  const float* eps = (const float*)d_in[12];
  float* out = (float*)d_out;

  char* ws = (char*)d_ws;
  unsigned* maskT     = (unsigned*)(ws + 0ull);                 // 1568*512*4   =  3,211,264
  unsigned short* BT1 = (unsigned short*)(ws + 3211264ull);     // 704*50176*2  = 70,647,808
  unsigned short* W2T = (unsigned short*)(ws + 73859072ull);    // 50048*640*2  = 64,061,440
  float* P            = (float*)(ws + 137920512ull);            // 512*704*4    =  1,441,792
  unsigned short* TB  = (unsigned short*)(ws + 139362304ull);   // 512*640*2    =    655,360
  float* cnt          = (float*)(ws + 140017664ull);            // 512*4

  float* outkl = out + (size_t)BB * NN;

  k_prep  <<<dim3(BB),       dim3(256), 0, stream>>>(inputs, maskT, cnt, P, outkl);
  k_convB1<<<dim3(784, 11),  dim3(256), 0, stream>>>(W1, item_emb, BT1);
  k_convB2<<<dim3(782, 10),  dim3(256), 0, stream>>>(Wd2, W2T);
  k_gemm1 <<<dim3(11, NCH),  dim3(512), 0, stream>>>(maskT, BT1, P);
  k_mid   <<<dim3(BB),       dim3(256), 0, stream>>>(P, cnt, W1, b1, Wm, bm, Wv, bv, Wd1, bd1, eps, TB, outkl);
  k_gemm2 <<<dim3(782),      dim3(512), 0, stream>>>(TB, W2T, bd2, out);
}